// Round 6
// baseline (261.085 us; speedup 1.0000x reference)
//
#include <hip/hip_runtime.h>
#include <hip/hip_bf16.h>

#define B_ 2
#define S_ 2048
#define D_ 1024
#define H_ 16
#define HD_ 64

typedef __attribute__((ext_vector_type(8))) short short8;
typedef __attribute__((ext_vector_type(4))) float f32x4;
typedef __attribute__((ext_vector_type(16))) float f32x16;
typedef __attribute__((ext_vector_type(4))) unsigned short us4;

static __device__ __forceinline__ ushort f2bf(float x) {
  __hip_bfloat16 h = __float2bfloat16(x);
  return *reinterpret_cast<ushort*>(&h);
}

static __device__ __forceinline__ void gld_lds16(void* lds, const void* g) {
  __builtin_amdgcn_global_load_lds(
      (__attribute__((address_space(1))) void*)(g),
      (__attribute__((address_space(3))) void*)(lds), 16, 0, 0);
}

// ---------------- conversion kernels ----------------

__global__ __launch_bounds__(256) void cvt_bf16_vec(const float4* __restrict__ in,
                                                    ushort* __restrict__ out, int n4) {
  int i = blockIdx.x * blockDim.x + threadIdx.x;
  if (i < n4) {
    float4 v = in[i];
    ushort4 o;
    o.x = f2bf(v.x); o.y = f2bf(v.y); o.z = f2bf(v.z); o.w = f2bf(v.w);
    *reinterpret_cast<ushort4*>(out + (size_t)i * 4) = o;
  }
}

// in: [K][N] f32 row-major  ->  out: [N][K] bf16 row-major
__global__ __launch_bounds__(256) void transpose_cvt(const float* __restrict__ in,
                                                     ushort* __restrict__ out,
                                                     int K, int N) {
  __shared__ float tile[32][33];
  const int bn = blockIdx.x * 32, bk = blockIdx.y * 32;
  const int tx = threadIdx.x, ty = threadIdx.y;
  #pragma unroll
  for (int i = ty; i < 32; i += 8)
    tile[i][tx] = in[(size_t)(bk + i) * N + bn + tx];
  __syncthreads();
  #pragma unroll
  for (int i = ty; i < 32; i += 8)
    out[(size_t)(bn + i) * K + bk + tx] = f2bf(tile[tx][i]);
}

// ---------------- GEMM: C = A @ Bt^T + bias ----------------
template <bool OUT_BF16>
__global__ __launch_bounds__(256) void gemm_bt(const ushort* __restrict__ A,
                                               const ushort* __restrict__ Bt,
                                               const float* __restrict__ bias,
                                               ushort* __restrict__ Cb,
                                               float* __restrict__ Cf,
                                               int M, int N, int K) {
  __shared__ __align__(16) ushort As[128 * 32];
  __shared__ __align__(16) ushort Bs[128 * 32];
  const int tid = threadIdx.x;
  const int lane = tid & 63, wid = tid >> 6;
  const int wr = wid >> 1, wc = wid & 1;
  const int row0 = blockIdx.x * 128, col0 = blockIdx.y * 128;
  const int l15 = lane & 15, lhi = lane >> 4;

  f32x4 acc[4][4];
  #pragma unroll
  for (int i = 0; i < 4; ++i)
    #pragma unroll
    for (int j = 0; j < 4; ++j)
      acc[i][j] = f32x4{0.f, 0.f, 0.f, 0.f};

  const int sr = tid >> 2;
  const int scol = (tid & 3) * 8;

  for (int k0 = 0; k0 < K; k0 += 32) {
    gld_lds16(&As[(size_t)tid * 8],        &A[(size_t)(row0 + sr) * K + k0 + scol]);
    gld_lds16(&As[2048 + (size_t)tid * 8], &A[(size_t)(row0 + 64 + sr) * K + k0 + scol]);
    gld_lds16(&Bs[(size_t)tid * 8],        &Bt[(size_t)(col0 + sr) * K + k0 + scol]);
    gld_lds16(&Bs[2048 + (size_t)tid * 8], &Bt[(size_t)(col0 + 64 + sr) * K + k0 + scol]);
    __syncthreads();

    short8 af[4], bfr[4];
    #pragma unroll
    for (int mt = 0; mt < 4; ++mt)
      af[mt] = *(const short8*)&As[(wr * 64 + mt * 16 + l15) * 32 + lhi * 8];
    #pragma unroll
    for (int nt = 0; nt < 4; ++nt)
      bfr[nt] = *(const short8*)&Bs[(wc * 64 + nt * 16 + l15) * 32 + lhi * 8];
    #pragma unroll
    for (int mt = 0; mt < 4; ++mt)
      #pragma unroll
      for (int nt = 0; nt < 4; ++nt)
        acc[mt][nt] = __builtin_amdgcn_mfma_f32_16x16x32_bf16(af[mt], bfr[nt], acc[mt][nt], 0, 0, 0);
    __syncthreads();
  }

  const int orow = row0 + wr * 64;
  const int ocol = col0 + wc * 64 + l15;
  #pragma unroll
  for (int mt = 0; mt < 4; ++mt) {
    #pragma unroll
    for (int nt = 0; nt < 4; ++nt) {
      const int gc = ocol + nt * 16;
      const float bv = bias[gc];
      #pragma unroll
      for (int r = 0; r < 4; ++r) {
        const int gr = orow + mt * 16 + lhi * 4 + r;
        const float v = acc[mt][nt][r] + bv;
        if (OUT_BF16) Cb[(size_t)gr * N + gc] = f2bf(v);
        else          Cf[(size_t)gr * N + gc] = v;
      }
    }
  }
}

// ---------------- flash attention, 32x32 MFMA, split-K over 2 key halves ----------------
// Round-4-proven 64-key tile body.  blockIdx.z = key-half; each block covers 1024 keys
// and writes unnormalized partial O (f32) + (m, l) per q-row; combine_halves merges.
// Defer-max (T13): skip o/l rescale while max grows by <= 8.
__global__ __launch_bounds__(256, 4) void flash_attn_split(const ushort* __restrict__ qkv,
                                                           const float* __restrict__ mask,
                                                           float* __restrict__ po,
                                                           float2* __restrict__ ml) {
  __shared__ __align__(16) ushort Ks[2][64 * 64];
  __shared__ __align__(16) ushort Vt[2][64 * 64];

  const int tid = threadIdx.x;
  const int lane = tid & 63, wid = tid >> 6;
  const int l31 = lane & 31, lhalf = lane >> 5;
  const int qt = blockIdx.x, bh = blockIdx.y, half = blockIdx.z;
  const int b = bh >> 4, h = bh & 15;
  const size_t base = (size_t)b * S_ * 3072 + (size_t)h * 192;
  const int q = qt * 128 + wid * 32 + l31;

  short8 qf[4];
  {
    const ushort* qrow = qkv + base + (size_t)q * 3072 + lhalf * 8;
    qf[0] = *(const short8*)(qrow);
    qf[1] = *(const short8*)(qrow + 16);
    qf[2] = *(const short8*)(qrow + 32);
    qf[3] = *(const short8*)(qrow + 48);
  }

  const int srow = tid >> 3, sch = tid & 7;
  const int hsr = (srow ^ (srow >> 3)) & 7;
  const int scs = sch ^ hsr;
  const int kg = tid & 15, d0 = (tid >> 4) * 4;
  const int skg = (kg & 12) | ((kg & 1) << 1) | ((kg >> 1) & 1);

  float m_run = -3.0e38f, l_run = 0.f;
  f32x16 o[2];
  #pragma unroll
  for (int dg = 0; dg < 2; ++dg)
    #pragma unroll
    for (int i = 0; i < 16; ++i) o[dg][i] = 0.f;

  const float* mrow = mask + ((size_t)b * S_ + q) * S_ + half * 1024;
  const int NT = 16;                    // 16 x 64 = 1024 keys per half
  int cur = 0;
  us4 vr[4];

  // per-iteration bumped pointers
  const ushort* kstage = qkv + base + (size_t)half * 1024 * 3072 + (size_t)srow * 3072 + 64;
  const ushort* vload  = qkv + base + (size_t)half * 1024 * 3072 + (size_t)(kg * 4) * 3072 + 128 + d0;

  // ---- prologue: stage tile 0 ----
  {
    gld_lds16(&Ks[0][tid * 8],        kstage + scs * 8);
    gld_lds16(&Ks[0][2048 + tid * 8], kstage + (size_t)32 * 3072 + (scs ^ 4) * 8);
    #pragma unroll
    for (int kk = 0; kk < 4; ++kk)
      vr[kk] = *(const us4*)(vload + (size_t)kk * 3072);
    kstage += (size_t)64 * 3072;
    vload  += (size_t)64 * 3072;
    #pragma unroll
    for (int dd = 0; dd < 4; ++dd) {
      const int d = d0 + dd;
      const int hd = (d ^ (d >> 3)) & 7;
      us4 w;
      w[0] = vr[0][dd]; w[1] = vr[1][dd]; w[2] = vr[2][dd]; w[3] = vr[3][dd];
      *(us4*)&Vt[0][d * 64 + (((skg >> 1) ^ hd) & 7) * 8 + (skg & 1) * 4] = w;
    }
    __syncthreads();
  }

  for (int kt = 0; kt < NT; ++kt) {
    const int nxt = cur ^ 1;
    const bool pre = (kt + 1 < NT);

    if (pre) {
      gld_lds16(&Ks[nxt][tid * 8],        kstage + scs * 8);
      gld_lds16(&Ks[nxt][2048 + tid * 8], kstage + (size_t)32 * 3072 + (scs ^ 4) * 8);
      #pragma unroll
      for (int kk = 0; kk < 4; ++kk)
        vr[kk] = *(const us4*)(vload + (size_t)kk * 3072);
      kstage += (size_t)64 * 3072;
      vload  += (size_t)64 * 3072;
    }

    // mask for current tile
    f32x4 mk[8];
    {
      const float* mp = mrow + kt * 64 + lhalf * 4;
      #pragma unroll
      for (int i = 0; i < 8; ++i)
        mk[i] = *(const f32x4*)(mp + (i >> 2) * 32 + (i & 3) * 8);
    }

    // ---- QK^T ----
    f32x16 sc[2];
    __builtin_amdgcn_s_setprio(1);
    #pragma unroll
    for (int g = 0; g < 2; ++g) {
      const int row = g * 32 + l31;
      const int hk = (row ^ (row >> 3)) & 7;
      const ushort* kp = &Ks[cur][row * 64];
      f32x16 s;
      #pragma unroll
      for (int i = 0; i < 16; ++i) s[i] = 0.f;
      #pragma unroll
      for (int kd = 0; kd < 4; ++kd) {
        short8 kf = *(const short8*)&kp[(((kd * 2 + lhalf) ^ hk) & 7) * 8];
        s = __builtin_amdgcn_mfma_f32_32x32x16_bf16(kf, qf[kd], s, 0, 0, 0);
      }
      sc[g] = s;
    }
    __builtin_amdgcn_s_setprio(0);

    // ---- scale + mask ----
    #pragma unroll
    for (int g = 0; g < 2; ++g)
      #pragma unroll
      for (int r = 0; r < 16; ++r)
        sc[g][r] = sc[g][r] * 0.125f + mk[g * 4 + (r >> 2)][r & 3];

    // ---- online softmax with defer-max ----
    float mx = sc[0][0];
    #pragma unroll
    for (int g = 0; g < 2; ++g)
      #pragma unroll
      for (int r = 0; r < 16; ++r) mx = fmaxf(mx, sc[g][r]);
    mx = fmaxf(mx, __shfl_xor(mx, 32));
    if (__any(mx > m_run + 8.0f)) {
      const float mnew = fmaxf(m_run, mx);
      const float alpha = __expf(m_run - mnew);
      m_run = mnew;
      l_run *= alpha;
      #pragma unroll
      for (int dg = 0; dg < 2; ++dg)
        #pragma unroll
        for (int i = 0; i < 16; ++i) o[dg][i] *= alpha;
    }
    float ps = 0.f;
    #pragma unroll
    for (int g = 0; g < 2; ++g)
      #pragma unroll
      for (int r = 0; r < 16; ++r) {
        const float p = __expf(sc[g][r] - m_run);
        sc[g][r] = p;
        ps += p;
      }
    ps += __shfl_xor(ps, 32);
    l_run += ps;

    // ---- P fragments (pi-permuted k-axis, in-register) ----
    short8 pf[4];
    #pragma unroll
    for (int ks = 0; ks < 4; ++ks)
      #pragma unroll
      for (int j = 0; j < 8; ++j)
        pf[ks][j] = (short)f2bf(sc[ks >> 1][8 * (ks & 1) + j]);

    // ---- PV ----
    __builtin_amdgcn_s_setprio(1);
    #pragma unroll
    for (int dg = 0; dg < 2; ++dg) {
      const int d = dg * 32 + l31;
      const int hv = (d ^ (d >> 3)) & 7;
      const ushort* vp = &Vt[cur][d * 64];
      #pragma unroll
      for (int ks = 0; ks < 4; ++ks) {
        short8 vf = *(const short8*)&vp[(((ks * 2 + lhalf) ^ hv) & 7) * 8];
        o[dg] = __builtin_amdgcn_mfma_f32_32x32x16_bf16(vf, pf[ks], o[dg], 0, 0, 0);
      }
    }
    __builtin_amdgcn_s_setprio(0);

    // ---- late V scatter into next buffer ----
    if (pre) {
      #pragma unroll
      for (int dd = 0; dd < 4; ++dd) {
        const int d = d0 + dd;
        const int hd = (d ^ (d >> 3)) & 7;
        us4 w;
        w[0] = vr[0][dd]; w[1] = vr[1][dd]; w[2] = vr[2][dd]; w[3] = vr[3][dd];
        *(us4*)&Vt[nxt][d * 64 + (((skg >> 1) ^ hd) & 7) * 8 + (skg & 1) * 4] = w;
      }
    }
    __syncthreads();
    cur = nxt;
  }

  // ---- epilogue: unnormalized partial O (f32) + (m,l) ----
  const size_t prow_i = (size_t)half * 65536 + (size_t)bh * S_ + q;
  float* prow = po + prow_i * 64;
  #pragma unroll
  for (int dg = 0; dg < 2; ++dg)
    #pragma unroll
    for (int quad = 0; quad < 4; ++quad) {
      f32x4 w;
      #pragma unroll
      for (int r = 0; r < 4; ++r) w[r] = o[dg][quad * 4 + r];
      *(f32x4*)(prow + dg * 32 + quad * 8 + lhalf * 4) = w;
    }
  if (lhalf == 0) ml[prow_i] = make_float2(m_run, l_run);
}

// merge the two key-half partials -> bf16 values [B*H][S][64]
__global__ __launch_bounds__(256) void combine_halves(const float* __restrict__ po,
                                                      const float2* __restrict__ ml,
                                                      ushort* __restrict__ vals) {
  const int idx = blockIdx.x * 256 + threadIdx.x;   // 65536*16 total
  const int qr = idx >> 4, c = idx & 15;
  const float2 a = ml[qr];
  const float2 bml = ml[65536 + qr];
  const float m = fmaxf(a.x, bml.x);
  const float w0 = __expf(a.x - m), w1 = __expf(bml.x - m);
  const float inv = 1.0f / (a.y * w0 + bml.y * w1);
  const f32x4 o0 = *(const f32x4*)(po + (size_t)qr * 64 + c * 4);
  const f32x4 o1 = *(const f32x4*)(po + (size_t)(65536 + qr) * 64 + c * 4);
  us4 w;
  #pragma unroll
  for (int r = 0; r < 4; ++r) w[r] = f2bf((o0[r] * w0 + o1[r] * w1) * inv);
  *(us4*)(vals + (size_t)qr * 64 + c * 4) = w;
}

// ---------------- fallback: round-4 single-pass flash attention ----------------
__global__ __launch_bounds__(256, 2) void flash_attn(const ushort* __restrict__ qkv,
                                                     const float* __restrict__ mask,
                                                     ushort* __restrict__ values) {
  __shared__ __align__(16) ushort Ks[2][64 * 64];
  __shared__ __align__(16) ushort Vt[2][64 * 64];

  const int tid = threadIdx.x;
  const int lane = tid & 63, wid = tid >> 6;
  const int l31 = lane & 31, lhalf = lane >> 5;
  const int qt = blockIdx.x, bh = blockIdx.y, b = bh >> 4, h = bh & 15;
  const size_t base = (size_t)b * S_ * 3072 + (size_t)h * 192;
  const int q = qt * 128 + wid * 32 + l31;

  short8 qf[4];
  {
    const ushort* qrow = qkv + base + (size_t)q * 3072 + lhalf * 8;
    qf[0] = *(const short8*)(qrow);
    qf[1] = *(const short8*)(qrow + 16);
    qf[2] = *(const short8*)(qrow + 32);
    qf[3] = *(const short8*)(qrow + 48);
  }

  const int srow = tid >> 3, sch = tid & 7;
  const int hsr = (srow ^ (srow >> 3)) & 7;
  const int scs = sch ^ hsr;
  const int kg = tid & 15, d0 = (tid >> 4) * 4;
  const int skg = (kg & 12) | ((kg & 1) << 1) | ((kg >> 1) & 1);

  float m_run = -3.0e38f, l_run = 0.f;
  f32x16 o[2];
  #pragma unroll
  for (int dg = 0; dg < 2; ++dg)
    #pragma unroll
    for (int i = 0; i < 16; ++i) o[dg][i] = 0.f;

  const float* mrow = mask + ((size_t)b * S_ + q) * S_;
  const int NT = S_ / 64;
  int cur = 0;
  us4 vr[4];

  {
    const ushort* kgp = qkv + base + (size_t)srow * 3072 + 64;
    gld_lds16(&Ks[0][tid * 8],        kgp + scs * 8);
    gld_lds16(&Ks[0][2048 + tid * 8], kgp + (size_t)32 * 3072 + (scs ^ 4) * 8);
    #pragma unroll
    for (int kk = 0; kk < 4; ++kk)
      vr[kk] = *(const us4*)(qkv + base + (size_t)(kg * 4 + kk) * 3072 + 128 + d0);
    #pragma unroll
    for (int dd = 0; dd < 4; ++dd) {
      const int d = d0 + dd;
      const int hd = (d ^ (d >> 3)) & 7;
      us4 w;
      w[0] = vr[0][dd]; w[1] = vr[1][dd]; w[2] = vr[2][dd]; w[3] = vr[3][dd];
      *(us4*)&Vt[0][d * 64 + (((skg >> 1) ^ hd) & 7) * 8 + (skg & 1) * 4] = w;
    }
    __syncthreads();
  }

  for (int kt = 0; kt < NT; ++kt) {
    const int nxt = cur ^ 1;
    const bool pre = (kt + 1 < NT);

    if (pre) {
      const size_t nb = base + (size_t)(kt + 1) * 64 * 3072;
      const ushort* kgp = qkv + nb + (size_t)srow * 3072 + 64;
      gld_lds16(&Ks[nxt][tid * 8],        kgp + scs * 8);
      gld_lds16(&Ks[nxt][2048 + tid * 8], kgp + (size_t)32 * 3072 + (scs ^ 4) * 8);
      #pragma unroll
      for (int kk = 0; kk < 4; ++kk)
        vr[kk] = *(const us4*)(qkv + nb + (size_t)(kg * 4 + kk) * 3072 + 128 + d0);
    }

    f32x4 mk[8];
    {
      const float* mp = mrow + kt * 64 + lhalf * 4;
      #pragma unroll
      for (int i = 0; i < 8; ++i)
        mk[i] = *(const f32x4*)(mp + (i >> 2) * 32 + (i & 3) * 8);
    }

    f32x16 sc[2];
    __builtin_amdgcn_s_setprio(1);
    #pragma unroll
    for (int g = 0; g < 2; ++g) {
      const int row = g * 32 + l31;
      const int hk = (row ^ (row >> 3)) & 7;
      const ushort* kp = &Ks[cur][row * 64];
      f32x16 s;
      #pragma unroll
      for (int i = 0; i < 16; ++i) s[i] = 0.f;
      #pragma unroll
      for (int kd = 0; kd < 4; ++kd) {
        short8 kf = *(const short8*)&kp[(((kd * 2 + lhalf) ^ hk) & 7) * 8];
        s = __builtin_amdgcn_mfma_f32_32x32x16_bf16(kf, qf[kd], s, 0, 0, 0);
      }
      sc[g] = s;
    }
    __builtin_amdgcn_s_setprio(0);

    #pragma unroll
    for (int g = 0; g < 2; ++g)
      #pragma unroll
      for (int r = 0; r < 16; ++r)
        sc[g][r] = sc[g][r] * 0.125f + mk[g * 4 + (r >> 2)][r & 3];

    float mx = sc[0][0];
    #pragma unroll
    for (int g = 0; g < 2; ++g)
      #pragma unroll
      for (int r = 0; r < 16; ++r) mx = fmaxf(mx, sc[g][r]);
    mx = fmaxf(mx, __shfl_xor(mx, 32));
    if (__any(mx > m_run + 8.0f)) {
      const float mnew = fmaxf(m_run, mx);
      const float alpha = __expf(m_run - mnew);
      m_run = mnew;
      l_run *= alpha;
      #pragma unroll
      for (int dg = 0; dg < 2; ++dg)
        #pragma unroll
        for (int i = 0; i < 16; ++i) o[dg][i] *= alpha;
    }
    float ps = 0.f;
    #pragma unroll
    for (int g = 0; g < 2; ++g)
      #pragma unroll
      for (int r = 0; r < 16; ++r) {
        const float p = __expf(sc[g][r] - m_run);
        sc[g][r] = p;
        ps += p;
      }
    ps += __shfl_xor(ps, 32);
    l_run += ps;

    short8 pf[4];
    #pragma unroll
    for (int ks = 0; ks < 4; ++ks)
      #pragma unroll
      for (int j = 0; j < 8; ++j)
        pf[ks][j] = (short)f2bf(sc[ks >> 1][8 * (ks & 1) + j]);

    __builtin_amdgcn_s_setprio(1);
    #pragma unroll
    for (int dg = 0; dg < 2; ++dg) {
      const int d = dg * 32 + l31;
      const int hv = (d ^ (d >> 3)) & 7;
      const ushort* vp = &Vt[cur][d * 64];
      #pragma unroll
      for (int ks = 0; ks < 4; ++ks) {
        short8 vf = *(const short8*)&vp[(((ks * 2 + lhalf) ^ hv) & 7) * 8];
        o[dg] = __builtin_amdgcn_mfma_f32_32x32x16_bf16(vf, pf[ks], o[dg], 0, 0, 0);
      }
    }
    __builtin_amdgcn_s_setprio(0);

    if (pre) {
      #pragma unroll
      for (int dd = 0; dd < 4; ++dd) {
        const int d = d0 + dd;
        const int hd = (d ^ (d >> 3)) & 7;
        us4 w;
        w[0] = vr[0][dd]; w[1] = vr[1][dd]; w[2] = vr[2][dd]; w[3] = vr[3][dd];
        *(us4*)&Vt[nxt][d * 64 + (((skg >> 1) ^ hd) & 7) * 8 + (skg & 1) * 4] = w;
      }
    }
    __syncthreads();
    cur = nxt;
  }

  const float inv = 1.0f / l_run;
  ushort* vout = values + ((size_t)bh * S_ + q) * 64;
  #pragma unroll
  for (int dg = 0; dg < 2; ++dg)
    #pragma unroll
    for (int quad = 0; quad < 4; ++quad) {
      us4 w;
      #pragma unroll
      for (int r = 0; r < 4; ++r) w[r] = f2bf(o[dg][quad * 4 + r] * inv);
      *(us4*)(vout + dg * 32 + quad * 8 + lhalf * 4) = w;
    }
}

// ---------------- launch ----------------

extern "C" void kernel_launch(void* const* d_in, const int* in_sizes, int n_in,
                              void* d_out, int out_size, void* d_ws, size_t ws_size,
                              hipStream_t stream) {
  const float* x    = (const float*)d_in[0];
  const float* mask = (const float*)d_in[1];
  const float* Wqkv = (const float*)d_in[2];
  const float* bqkv = (const float*)d_in[3];
  const float* Wo   = (const float*)d_in[4];
  const float* bo   = (const float*)d_in[5];
  float* out = (float*)d_out;

  char* ws = (char*)d_ws;
  // layout:
  //   [0, 8388608)          x_bf, later aliased by values
  //   [8388608, 14680064)   WqkvT bf16
  //   [14680064, 16777216)  WoT   bf16
  //   [16777216, 41943040)  qkv   bf16
  //   [41943040, 75497472)  po    f32  [2][65536][64]   (split path only)
  //   [75497472, 76546048)  ml    f32x2 [2][65536]      (split path only)
  ushort* xbf    = (ushort*)(ws + 0);
  ushort* vals   = (ushort*)(ws + 0);
  ushort* wqkvT  = (ushort*)(ws + 8388608);
  ushort* woT    = (ushort*)(ws + 14680064);
  ushort* qkv    = (ushort*)(ws + 16777216);
  float*  po     = (float*)(ws + 41943040);
  float2* ml     = (float2*)(ws + 75497472);
  const bool split_ok = (ws_size >= 76546048ull);

  cvt_bf16_vec<<<4096, 256, 0, stream>>>((const float4*)x, xbf, (B_ * S_ * D_) / 4);
  transpose_cvt<<<dim3(3 * D_ / 32, D_ / 32), dim3(32, 8), 0, stream>>>(Wqkv, wqkvT, D_, 3 * D_);
  transpose_cvt<<<dim3(D_ / 32, D_ / 32), dim3(32, 8), 0, stream>>>(Wo, woT, D_, D_);
  gemm_bt<true><<<dim3((B_ * S_) / 128, (3 * D_) / 128), 256, 0, stream>>>(
      xbf, wqkvT, bqkv, qkv, nullptr, B_ * S_, 3 * D_, D_);
  if (split_ok) {
    flash_attn_split<<<dim3(S_ / 128, B_ * H_, 2), 256, 0, stream>>>(qkv, mask, po, ml);
    combine_halves<<<4096, 256, 0, stream>>>(po, ml, vals);
  } else {
    flash_attn<<<dim3(S_ / 128, B_ * H_), 256, 0, stream>>>(qkv, mask, vals);
  }
  gemm_bt<false><<<dim3((B_ * S_) / 128, D_ / 128), 256, 0, stream>>>(
      vals, woT, bo, nullptr, out, B_ * S_, D_, D_);
}

// Round 7
// 191.015 us; speedup vs baseline: 1.3668x; 1.3668x over previous
//
#include <hip/hip_runtime.h>
#include <hip/hip_bf16.h>

#define B_ 2
#define S_ 2048
#define D_ 1024
#define H_ 16
#define HD_ 64

typedef __attribute__((ext_vector_type(8))) short short8;
typedef __attribute__((ext_vector_type(4))) float f32x4;
typedef __attribute__((ext_vector_type(16))) float f32x16;
typedef __attribute__((ext_vector_type(4))) unsigned short us4;

static __device__ __forceinline__ ushort f2bf(float x) {
  __hip_bfloat16 h = __float2bfloat16(x);
  return *reinterpret_cast<ushort*>(&h);
}

static __device__ __forceinline__ void gld_lds16(void* lds, const void* g) {
  __builtin_amdgcn_global_load_lds(
      (__attribute__((address_space(1))) void*)(g),
      (__attribute__((address_space(3))) void*)(lds), 16, 0, 0);
}

// ---------------- conversion kernels ----------------

__global__ __launch_bounds__(256) void cvt_bf16_vec(const float4* __restrict__ in,
                                                    ushort* __restrict__ out, int n4) {
  int i = blockIdx.x * blockDim.x + threadIdx.x;
  if (i < n4) {
    float4 v = in[i];
    ushort4 o;
    o.x = f2bf(v.x); o.y = f2bf(v.y); o.z = f2bf(v.z); o.w = f2bf(v.w);
    *reinterpret_cast<ushort4*>(out + (size_t)i * 4) = o;
  }
}

// in: [K][N] f32 row-major  ->  out: [N][K] bf16 row-major
__global__ __launch_bounds__(256) void transpose_cvt(const float* __restrict__ in,
                                                     ushort* __restrict__ out,
                                                     int K, int N) {
  __shared__ float tile[32][33];
  const int bn = blockIdx.x * 32, bk = blockIdx.y * 32;
  const int tx = threadIdx.x, ty = threadIdx.y;
  #pragma unroll
  for (int i = ty; i < 32; i += 8)
    tile[i][tx] = in[(size_t)(bk + i) * N + bn + tx];
  __syncthreads();
  #pragma unroll
  for (int i = ty; i < 32; i += 8)
    out[(size_t)(bn + i) * K + bk + tx] = f2bf(tile[tx][i]);
}

// ---------------- GEMM: C = A @ Bt^T + bias ----------------
template <bool OUT_BF16>
__global__ __launch_bounds__(256) void gemm_bt(const ushort* __restrict__ A,
                                               const ushort* __restrict__ Bt,
                                               const float* __restrict__ bias,
                                               ushort* __restrict__ Cb,
                                               float* __restrict__ Cf,
                                               int M, int N, int K) {
  __shared__ __align__(16) ushort As[128 * 32];
  __shared__ __align__(16) ushort Bs[128 * 32];
  const int tid = threadIdx.x;
  const int lane = tid & 63, wid = tid >> 6;
  const int wr = wid >> 1, wc = wid & 1;
  const int row0 = blockIdx.x * 128, col0 = blockIdx.y * 128;
  const int l15 = lane & 15, lhi = lane >> 4;

  f32x4 acc[4][4];
  #pragma unroll
  for (int i = 0; i < 4; ++i)
    #pragma unroll
    for (int j = 0; j < 4; ++j)
      acc[i][j] = f32x4{0.f, 0.f, 0.f, 0.f};

  const int sr = tid >> 2;
  const int scol = (tid & 3) * 8;

  for (int k0 = 0; k0 < K; k0 += 32) {
    gld_lds16(&As[(size_t)tid * 8],        &A[(size_t)(row0 + sr) * K + k0 + scol]);
    gld_lds16(&As[2048 + (size_t)tid * 8], &A[(size_t)(row0 + 64 + sr) * K + k0 + scol]);
    gld_lds16(&Bs[(size_t)tid * 8],        &Bt[(size_t)(col0 + sr) * K + k0 + scol]);
    gld_lds16(&Bs[2048 + (size_t)tid * 8], &Bt[(size_t)(col0 + 64 + sr) * K + k0 + scol]);
    __syncthreads();

    short8 af[4], bfr[4];
    #pragma unroll
    for (int mt = 0; mt < 4; ++mt)
      af[mt] = *(const short8*)&As[(wr * 64 + mt * 16 + l15) * 32 + lhi * 8];
    #pragma unroll
    for (int nt = 0; nt < 4; ++nt)
      bfr[nt] = *(const short8*)&Bs[(wc * 64 + nt * 16 + l15) * 32 + lhi * 8];
    #pragma unroll
    for (int mt = 0; mt < 4; ++mt)
      #pragma unroll
      for (int nt = 0; nt < 4; ++nt)
        acc[mt][nt] = __builtin_amdgcn_mfma_f32_16x16x32_bf16(af[mt], bfr[nt], acc[mt][nt], 0, 0, 0);
    __syncthreads();
  }

  const int orow = row0 + wr * 64;
  const int ocol = col0 + wc * 64 + l15;
  #pragma unroll
  for (int mt = 0; mt < 4; ++mt) {
    #pragma unroll
    for (int nt = 0; nt < 4; ++nt) {
      const int gc = ocol + nt * 16;
      const float bv = bias[gc];
      #pragma unroll
      for (int r = 0; r < 4; ++r) {
        const int gr = orow + mt * 16 + lhi * 4 + r;
        const float v = acc[mt][nt][r] + bv;
        if (OUT_BF16) Cb[(size_t)gr * N + gc] = f2bf(v);
        else          Cf[(size_t)gr * N + gc] = v;
      }
    }
  }
}

// ---------------- flash attention, 32x32 MFMA, 32 q-rows/wave ----------------
// Round-4 verified body + (a) mask double-buffer prefetch (mk/mkn) so the 67MB
// mask stream has a full iteration of latency cover, (b) V fragment ds_reads
// hoisted before softmax so PV is a pure MFMA cluster, (c) defer-max (T13).
__global__ __launch_bounds__(256, 2) void flash_attn(const ushort* __restrict__ qkv,
                                                     const float* __restrict__ mask,
                                                     ushort* __restrict__ values) {
  __shared__ __align__(16) ushort Ks[2][64 * 64];
  __shared__ __align__(16) ushort Vt[2][64 * 64];

  const int tid = threadIdx.x;
  const int lane = tid & 63, wid = tid >> 6;
  const int l31 = lane & 31, lhalf = lane >> 5;
  const int qt = blockIdx.x, bh = blockIdx.y, b = bh >> 4, h = bh & 15;
  const size_t base = (size_t)b * S_ * 3072 + (size_t)h * 192;
  const int q = qt * 128 + wid * 32 + l31;

  // Q B-frags: qf[kd] = Q[q][kd*16 + lhalf*8 + 0..7]
  short8 qf[4];
  {
    const ushort* qrow = qkv + base + (size_t)q * 3072 + lhalf * 8;
    qf[0] = *(const short8*)(qrow);
    qf[1] = *(const short8*)(qrow + 16);
    qf[2] = *(const short8*)(qrow + 32);
    qf[3] = *(const short8*)(qrow + 48);
  }

  const int srow = tid >> 3, sch = tid & 7;
  const int hsr = (srow ^ (srow >> 3)) & 7;
  const int scs = sch ^ hsr;
  const int kg = tid & 15, d0 = (tid >> 4) * 4;
  const int skg = (kg & 12) | ((kg & 1) << 1) | ((kg >> 1) & 1);

  float m_run = -3.0e38f, l_run = 0.f;
  f32x16 o[2];
  #pragma unroll
  for (int dg = 0; dg < 2; ++dg)
    #pragma unroll
    for (int i = 0; i < 16; ++i) o[dg][i] = 0.f;

  const float* mrow = mask + ((size_t)b * S_ + q) * S_;
  f32x4 mk[8], mkn[8];
  const int NT = S_ / 64;
  int cur = 0;
  us4 vr[4];

  // ---- prologue: stage tile 0 + mask tile 0 ----
  {
    const ushort* kgp = qkv + base + (size_t)srow * 3072 + 64;
    gld_lds16(&Ks[0][tid * 8],        kgp + scs * 8);
    gld_lds16(&Ks[0][2048 + tid * 8], kgp + (size_t)32 * 3072 + (scs ^ 4) * 8);
    #pragma unroll
    for (int kk = 0; kk < 4; ++kk)
      vr[kk] = *(const us4*)(qkv + base + (size_t)(kg * 4 + kk) * 3072 + 128 + d0);
    #pragma unroll
    for (int i = 0; i < 8; ++i)
      mk[i] = *(const f32x4*)(mrow + (i >> 2) * 32 + (i & 3) * 8 + lhalf * 4);
    #pragma unroll
    for (int dd = 0; dd < 4; ++dd) {
      const int d = d0 + dd;
      const int hd = (d ^ (d >> 3)) & 7;
      us4 w;
      w[0] = vr[0][dd]; w[1] = vr[1][dd]; w[2] = vr[2][dd]; w[3] = vr[3][dd];
      *(us4*)&Vt[0][d * 64 + (((skg >> 1) ^ hd) & 7) * 8 + (skg & 1) * 4] = w;
    }
    __syncthreads();
  }

  for (int kt = 0; kt < NT; ++kt) {
    const int nxt = cur ^ 1;
    const bool pre = (kt + 1 < NT);

    // ---- early: issue next-tile K gld_lds + V reg loads + mask prefetch ----
    if (pre) {
      const size_t nb = base + (size_t)(kt + 1) * 64 * 3072;
      const ushort* kgp = qkv + nb + (size_t)srow * 3072 + 64;
      gld_lds16(&Ks[nxt][tid * 8],        kgp + scs * 8);
      gld_lds16(&Ks[nxt][2048 + tid * 8], kgp + (size_t)32 * 3072 + (scs ^ 4) * 8);
      #pragma unroll
      for (int kk = 0; kk < 4; ++kk)
        vr[kk] = *(const us4*)(qkv + nb + (size_t)(kg * 4 + kk) * 3072 + 128 + d0);
      const float* mn = mrow + (size_t)(kt + 1) * 64;
      #pragma unroll
      for (int i = 0; i < 8; ++i)
        mkn[i] = *(const f32x4*)(mn + (i >> 2) * 32 + (i & 3) * 8 + lhalf * 4);
    }

    // ---- QK^T ----
    f32x16 sc[2];
    __builtin_amdgcn_s_setprio(1);
    #pragma unroll
    for (int g = 0; g < 2; ++g) {
      const int row = g * 32 + l31;
      const int hk = (row ^ (row >> 3)) & 7;
      const ushort* kp = &Ks[cur][row * 64];
      f32x16 s;
      #pragma unroll
      for (int i = 0; i < 16; ++i) s[i] = 0.f;
      #pragma unroll
      for (int kd = 0; kd < 4; ++kd) {
        short8 kf = *(const short8*)&kp[(((kd * 2 + lhalf) ^ hk) & 7) * 8];
        s = __builtin_amdgcn_mfma_f32_32x32x16_bf16(kf, qf[kd], s, 0, 0, 0);
      }
      sc[g] = s;
    }
    __builtin_amdgcn_s_setprio(0);

    // ---- hoist V(cur) fragment reads: latency hides under softmax ----
    short8 vf[2][4];
    #pragma unroll
    for (int dg = 0; dg < 2; ++dg) {
      const int d = dg * 32 + l31;
      const int hv = (d ^ (d >> 3)) & 7;
      const ushort* vp = &Vt[cur][d * 64];
      #pragma unroll
      for (int ks = 0; ks < 4; ++ks)
        vf[dg][ks] = *(const short8*)&vp[(((ks * 2 + lhalf) ^ hv) & 7) * 8];
    }

    // ---- scale + mask (mk preloaded one tile ahead) ----
    #pragma unroll
    for (int g = 0; g < 2; ++g)
      #pragma unroll
      for (int r = 0; r < 16; ++r)
        sc[g][r] = sc[g][r] * 0.125f + mk[g * 4 + (r >> 2)][r & 3];

    // ---- online softmax with defer-max (per-lane q; 1 shfl) ----
    float mx = sc[0][0];
    #pragma unroll
    for (int g = 0; g < 2; ++g)
      #pragma unroll
      for (int r = 0; r < 16; ++r) mx = fmaxf(mx, sc[g][r]);
    mx = fmaxf(mx, __shfl_xor(mx, 32));
    if (__any(mx > m_run + 8.0f)) {
      const float mnew = fmaxf(m_run, mx);
      const float alpha = __expf(m_run - mnew);
      m_run = mnew;
      l_run *= alpha;
      #pragma unroll
      for (int dg = 0; dg < 2; ++dg)
        #pragma unroll
        for (int i = 0; i < 16; ++i) o[dg][i] *= alpha;
    }
    float ps = 0.f;
    #pragma unroll
    for (int g = 0; g < 2; ++g)
      #pragma unroll
      for (int r = 0; r < 16; ++r) {
        const float p = __expf(sc[g][r] - m_run);
        sc[g][r] = p;
        ps += p;
      }
    ps += __shfl_xor(ps, 32);
    l_run += ps;

    // ---- P fragments (pi-permuted k-axis, in-register) ----
    short8 pf[4];
    #pragma unroll
    for (int ks = 0; ks < 4; ++ks)
      #pragma unroll
      for (int j = 0; j < 8; ++j)
        pf[ks][j] = (short)f2bf(sc[ks >> 1][8 * (ks & 1) + j]);

    // ---- PV: pure MFMA cluster ----
    __builtin_amdgcn_s_setprio(1);
    #pragma unroll
    for (int dg = 0; dg < 2; ++dg)
      #pragma unroll
      for (int ks = 0; ks < 4; ++ks)
        o[dg] = __builtin_amdgcn_mfma_f32_32x32x16_bf16(vf[dg][ks], pf[ks], o[dg], 0, 0, 0);
    __builtin_amdgcn_s_setprio(0);

    // ---- late: V register-transpose into Vt[nxt]; rotate mask regs ----
    if (pre) {
      #pragma unroll
      for (int dd = 0; dd < 4; ++dd) {
        const int d = d0 + dd;
        const int hd = (d ^ (d >> 3)) & 7;
        us4 w;
        w[0] = vr[0][dd]; w[1] = vr[1][dd]; w[2] = vr[2][dd]; w[3] = vr[3][dd];
        *(us4*)&Vt[nxt][d * 64 + (((skg >> 1) ^ hd) & 7) * 8 + (skg & 1) * 4] = w;
      }
      #pragma unroll
      for (int i = 0; i < 8; ++i) mk[i] = mkn[i];
    }
    __syncthreads();
    cur = nxt;
  }

  // ---- epilogue: O^T/l -> values[bh][q][d] ----
  const float inv = 1.0f / l_run;
  ushort* vout = values + ((size_t)bh * S_ + q) * 64;
  #pragma unroll
  for (int dg = 0; dg < 2; ++dg)
    #pragma unroll
    for (int quad = 0; quad < 4; ++quad) {
      us4 w;
      #pragma unroll
      for (int r = 0; r < 4; ++r) w[r] = f2bf(o[dg][quad * 4 + r] * inv);
      *(us4*)(vout + dg * 32 + quad * 8 + lhalf * 4) = w;
    }
}

// ---------------- launch ----------------

extern "C" void kernel_launch(void* const* d_in, const int* in_sizes, int n_in,
                              void* d_out, int out_size, void* d_ws, size_t ws_size,
                              hipStream_t stream) {
  const float* x    = (const float*)d_in[0];
  const float* mask = (const float*)d_in[1];
  const float* Wqkv = (const float*)d_in[2];
  const float* bqkv = (const float*)d_in[3];
  const float* Wo   = (const float*)d_in[4];
  const float* bo   = (const float*)d_in[5];
  float* out = (float*)d_out;

  char* ws = (char*)d_ws;
  ushort* xbf    = (ushort*)(ws + 0);
  ushort* vals   = (ushort*)(ws + 0);
  ushort* wqkvT  = (ushort*)(ws + 8388608);
  ushort* woT    = (ushort*)(ws + 14680064);
  ushort* qkv    = (ushort*)(ws + 16777216);

  cvt_bf16_vec<<<4096, 256, 0, stream>>>((const float4*)x, xbf, (B_ * S_ * D_) / 4);
  transpose_cvt<<<dim3(3 * D_ / 32, D_ / 32), dim3(32, 8), 0, stream>>>(Wqkv, wqkvT, D_, 3 * D_);
  transpose_cvt<<<dim3(D_ / 32, D_ / 32), dim3(32, 8), 0, stream>>>(Wo, woT, D_, D_);
  gemm_bt<true><<<dim3((B_ * S_) / 128, (3 * D_) / 128), 256, 0, stream>>>(
      xbf, wqkvT, bqkv, qkv, nullptr, B_ * S_, 3 * D_, D_);
  flash_attn<<<dim3(S_ / 128, B_ * H_), 256, 0, stream>>>(qkv, mask, vals);
  gemm_bt<false><<<dim3((B_ * S_) / 128, D_ / 128), 256, 0, stream>>>(
      vals, woT, bo, nullptr, out, B_ * S_, D_, D_);
}

// Round 8
// 189.440 us; speedup vs baseline: 1.3782x; 1.0083x over previous
//
#include <hip/hip_runtime.h>
#include <hip/hip_bf16.h>

#define B_ 2
#define S_ 2048
#define D_ 1024
#define H_ 16
#define HD_ 64

typedef __attribute__((ext_vector_type(8))) short short8;
typedef __attribute__((ext_vector_type(4))) float f32x4;
typedef __attribute__((ext_vector_type(16))) float f32x16;
typedef __attribute__((ext_vector_type(4))) unsigned short us4;

static __device__ __forceinline__ ushort f2bf(float x) {
  __hip_bfloat16 h = __float2bfloat16(x);
  return *reinterpret_cast<ushort*>(&h);
}

static __device__ __forceinline__ void gld_lds16(void* lds, const void* g) {
  __builtin_amdgcn_global_load_lds(
      (__attribute__((address_space(1))) void*)(g),
      (__attribute__((address_space(3))) void*)(lds), 16, 0, 0);
}

// ---------------- conversion kernels ----------------

__global__ __launch_bounds__(256) void cvt_bf16_vec(const float4* __restrict__ in,
                                                    ushort* __restrict__ out, int n4) {
  int i = blockIdx.x * blockDim.x + threadIdx.x;
  if (i < n4) {
    float4 v = in[i];
    ushort4 o;
    o.x = f2bf(v.x); o.y = f2bf(v.y); o.z = f2bf(v.z); o.w = f2bf(v.w);
    *reinterpret_cast<ushort4*>(out + (size_t)i * 4) = o;
  }
}

// in: [K][N] f32 row-major  ->  out: [N][K] bf16 row-major
__global__ __launch_bounds__(256) void transpose_cvt(const float* __restrict__ in,
                                                     ushort* __restrict__ out,
                                                     int K, int N) {
  __shared__ float tile[32][33];
  const int bn = blockIdx.x * 32, bk = blockIdx.y * 32;
  const int tx = threadIdx.x, ty = threadIdx.y;
  #pragma unroll
  for (int i = ty; i < 32; i += 8)
    tile[i][tx] = in[(size_t)(bk + i) * N + bn + tx];
  __syncthreads();
  #pragma unroll
  for (int i = ty; i < 32; i += 8)
    out[(size_t)(bn + i) * K + bk + tx] = f2bf(tile[tx][i]);
}

// ---------------- GEMM: C = A @ Bt^T + bias ----------------
template <bool OUT_BF16>
__global__ __launch_bounds__(256) void gemm_bt(const ushort* __restrict__ A,
                                               const ushort* __restrict__ Bt,
                                               const float* __restrict__ bias,
                                               ushort* __restrict__ Cb,
                                               float* __restrict__ Cf,
                                               int M, int N, int K) {
  __shared__ __align__(16) ushort As[128 * 32];
  __shared__ __align__(16) ushort Bs[128 * 32];
  const int tid = threadIdx.x;
  const int lane = tid & 63, wid = tid >> 6;
  const int wr = wid >> 1, wc = wid & 1;
  const int row0 = blockIdx.x * 128, col0 = blockIdx.y * 128;
  const int l15 = lane & 15, lhi = lane >> 4;

  f32x4 acc[4][4];
  #pragma unroll
  for (int i = 0; i < 4; ++i)
    #pragma unroll
    for (int j = 0; j < 4; ++j)
      acc[i][j] = f32x4{0.f, 0.f, 0.f, 0.f};

  const int sr = tid >> 2;
  const int scol = (tid & 3) * 8;

  for (int k0 = 0; k0 < K; k0 += 32) {
    gld_lds16(&As[(size_t)tid * 8],        &A[(size_t)(row0 + sr) * K + k0 + scol]);
    gld_lds16(&As[2048 + (size_t)tid * 8], &A[(size_t)(row0 + 64 + sr) * K + k0 + scol]);
    gld_lds16(&Bs[(size_t)tid * 8],        &Bt[(size_t)(col0 + sr) * K + k0 + scol]);
    gld_lds16(&Bs[2048 + (size_t)tid * 8], &Bt[(size_t)(col0 + 64 + sr) * K + k0 + scol]);
    __syncthreads();

    short8 af[4], bfr[4];
    #pragma unroll
    for (int mt = 0; mt < 4; ++mt)
      af[mt] = *(const short8*)&As[(wr * 64 + mt * 16 + l15) * 32 + lhi * 8];
    #pragma unroll
    for (int nt = 0; nt < 4; ++nt)
      bfr[nt] = *(const short8*)&Bs[(wc * 64 + nt * 16 + l15) * 32 + lhi * 8];
    #pragma unroll
    for (int mt = 0; mt < 4; ++mt)
      #pragma unroll
      for (int nt = 0; nt < 4; ++nt)
        acc[mt][nt] = __builtin_amdgcn_mfma_f32_16x16x32_bf16(af[mt], bfr[nt], acc[mt][nt], 0, 0, 0);
    __syncthreads();
  }

  const int orow = row0 + wr * 64;
  const int ocol = col0 + wc * 64 + l15;
  #pragma unroll
  for (int mt = 0; mt < 4; ++mt) {
    #pragma unroll
    for (int nt = 0; nt < 4; ++nt) {
      const int gc = ocol + nt * 16;
      const float bv = bias[gc];
      #pragma unroll
      for (int r = 0; r < 4; ++r) {
        const int gr = orow + mt * 16 + lhi * 4 + r;
        const float v = acc[mt][nt][r] + bv;
        if (OUT_BF16) Cb[(size_t)gr * N + gc] = f2bf(v);
        else          Cf[(size_t)gr * N + gc] = v;
      }
    }
  }
}

// ---------------- flash attention, 32x32 MFMA, KVBLK=128, reg-staged K ----------------
// Round-4 verified per-64-key sub-tile layouts and math.  Changes:
//  * 128 keys staged per LDS buffer, processed as two sequential 64-key passes
//    sharing one barrier (16 barriers instead of 32).
//  * K staged via registers (global->VGPR at iter top, ds_write after PV) so the
//    barrier needs no vmcnt(0) drain of in-flight prefetch (T14 full split).
//  * Both passes' mask registers issued at iteration top (no rotate movs).
//  * Defer-max (T13, THR=8).
__global__ __launch_bounds__(256, 2) void flash_attn(const ushort* __restrict__ qkv,
                                                     const float* __restrict__ mask,
                                                     ushort* __restrict__ values) {
  __shared__ __align__(16) ushort Ks[2][2][64 * 64];
  __shared__ __align__(16) ushort Vt[2][2][64 * 64];

  const int tid = threadIdx.x;
  const int lane = tid & 63, wid = tid >> 6;
  const int l31 = lane & 31, lhalf = lane >> 5;
  const int qt = blockIdx.x, bh = blockIdx.y, b = bh >> 4, h = bh & 15;
  const size_t base = (size_t)b * S_ * 3072 + (size_t)h * 192;
  const int q = qt * 128 + wid * 32 + l31;

  // Q B-frags: qf[kd] = Q[q][kd*16 + lhalf*8 + 0..7]
  short8 qf[4];
  {
    const ushort* qrow = qkv + base + (size_t)q * 3072 + lhalf * 8;
    qf[0] = *(const short8*)(qrow);
    qf[1] = *(const short8*)(qrow + 16);
    qf[2] = *(const short8*)(qrow + 32);
    qf[3] = *(const short8*)(qrow + 48);
  }

  // K staging (per 64-row sub-tile): thread -> (srow 0..31, chunk sch 0..7)
  const int srow = tid >> 3, sch = tid & 7;
  const int hsr = (srow ^ (srow >> 3)) & 7;
  const int scs = sch ^ hsr;                 // rows 32..63 use scs^4
  // V staging: thread owns 4 keys x 4 d per sub-tile; column relabel sigma(kg)
  const int kg = tid & 15, d0 = (tid >> 4) * 4;
  const int skg = (kg & 12) | ((kg & 1) << 1) | ((kg >> 1) & 1);

  float m_run = -3.0e38f, l_run = 0.f;
  f32x16 o[2];
  #pragma unroll
  for (int dg = 0; dg < 2; ++dg)
    #pragma unroll
    for (int i = 0; i < 16; ++i) o[dg][i] = 0.f;

  const float* mrow = mask + ((size_t)b * S_ + q) * S_;
  const int NT2 = S_ / 128;
  int cur = 0;
  short8 kr[4];
  us4 vr[8];

  // ---- prologue: stage tile 0 (both sub-tiles) via gld_lds (one-time) ----
  {
    #pragma unroll
    for (int s2 = 0; s2 < 2; ++s2) {
      const ushort* kgp = qkv + base + (size_t)(s2 * 64 + srow) * 3072 + 64;
      gld_lds16(&Ks[0][s2][tid * 8],        kgp + scs * 8);
      gld_lds16(&Ks[0][s2][2048 + tid * 8], kgp + (size_t)32 * 3072 + (scs ^ 4) * 8);
      #pragma unroll
      for (int kk = 0; kk < 4; ++kk)
        vr[s2 * 4 + kk] = *(const us4*)(qkv + base +
                           (size_t)(s2 * 64 + kg * 4 + kk) * 3072 + 128 + d0);
    }
    #pragma unroll
    for (int s2 = 0; s2 < 2; ++s2)
      #pragma unroll
      for (int dd = 0; dd < 4; ++dd) {
        const int d = d0 + dd;
        const int hd = (d ^ (d >> 3)) & 7;
        us4 w;
        w[0] = vr[s2 * 4 + 0][dd]; w[1] = vr[s2 * 4 + 1][dd];
        w[2] = vr[s2 * 4 + 2][dd]; w[3] = vr[s2 * 4 + 3][dd];
        *(us4*)&Vt[0][s2][d * 64 + (((skg >> 1) ^ hd) & 7) * 8 + (skg & 1) * 4] = w;
      }
    __syncthreads();
  }

  for (int t = 0; t < NT2; ++t) {
    const int nxt = cur ^ 1;
    const bool pre = (t + 1 < NT2);

    // ---- iteration top: issue ALL prefetch (K->reg, V->reg, both mask sets) ----
    if (pre) {
      const size_t nb = base + (size_t)(t + 1) * 128 * 3072;
      // K next: exact pre-swizzled addresses gld_lds used, now into registers
      kr[0] = *(const short8*)(qkv + nb + (size_t)(srow)      * 3072 + 64 + scs * 8);
      kr[1] = *(const short8*)(qkv + nb + (size_t)(32 + srow) * 3072 + 64 + (scs ^ 4) * 8);
      kr[2] = *(const short8*)(qkv + nb + (size_t)(64 + srow) * 3072 + 64 + scs * 8);
      kr[3] = *(const short8*)(qkv + nb + (size_t)(96 + srow) * 3072 + 64 + (scs ^ 4) * 8);
      #pragma unroll
      for (int s2 = 0; s2 < 2; ++s2)
        #pragma unroll
        for (int kk = 0; kk < 4; ++kk)
          vr[s2 * 4 + kk] = *(const us4*)(qkv + nb +
                             (size_t)(s2 * 64 + kg * 4 + kk) * 3072 + 128 + d0);
    }
    f32x4 mka[8], mkb[8];
    {
      const float* mp = mrow + (size_t)t * 128 + lhalf * 4;
      #pragma unroll
      for (int i = 0; i < 8; ++i)
        mka[i] = *(const f32x4*)(mp + (i >> 2) * 32 + (i & 3) * 8);
      #pragma unroll
      for (int i = 0; i < 8; ++i)
        mkb[i] = *(const f32x4*)(mp + 64 + (i >> 2) * 32 + (i & 3) * 8);
    }

    // ==== two sequential 64-key passes over Ks[cur][s2] / Vt[cur][s2] ====
    #pragma unroll
    for (int s2 = 0; s2 < 2; ++s2) {
      const f32x4* mk = (s2 == 0) ? mka : mkb;

      // ---- QK^T ----
      f32x16 sc[2];
      __builtin_amdgcn_s_setprio(1);
      #pragma unroll
      for (int g = 0; g < 2; ++g) {
        const int row = g * 32 + l31;
        const int hk = (row ^ (row >> 3)) & 7;
        const ushort* kp = &Ks[cur][s2][row * 64];
        f32x16 s;
        #pragma unroll
        for (int i = 0; i < 16; ++i) s[i] = 0.f;
        #pragma unroll
        for (int kd = 0; kd < 4; ++kd) {
          short8 kf = *(const short8*)&kp[(((kd * 2 + lhalf) ^ hk) & 7) * 8];
          s = __builtin_amdgcn_mfma_f32_32x32x16_bf16(kf, qf[kd], s, 0, 0, 0);
        }
        sc[g] = s;
      }
      __builtin_amdgcn_s_setprio(0);

      // ---- scale + mask ----
      #pragma unroll
      for (int g = 0; g < 2; ++g)
        #pragma unroll
        for (int r = 0; r < 16; ++r)
          sc[g][r] = sc[g][r] * 0.125f + mk[g * 4 + (r >> 2)][r & 3];

      // ---- online softmax with defer-max (per-lane q; 1 shfl) ----
      float mx = sc[0][0];
      #pragma unroll
      for (int g = 0; g < 2; ++g)
        #pragma unroll
        for (int r = 0; r < 16; ++r) mx = fmaxf(mx, sc[g][r]);
      mx = fmaxf(mx, __shfl_xor(mx, 32));
      if (__any(mx > m_run + 8.0f)) {
        const float mnew = fmaxf(m_run, mx);
        const float alpha = __expf(m_run - mnew);
        m_run = mnew;
        l_run *= alpha;
        #pragma unroll
        for (int dg = 0; dg < 2; ++dg)
          #pragma unroll
          for (int i = 0; i < 16; ++i) o[dg][i] *= alpha;
      }
      float ps = 0.f;
      #pragma unroll
      for (int g = 0; g < 2; ++g)
        #pragma unroll
        for (int r = 0; r < 16; ++r) {
          const float p = __expf(sc[g][r] - m_run);
          sc[g][r] = p;
          ps += p;
        }
      ps += __shfl_xor(ps, 32);
      l_run += ps;

      // ---- P fragments (pi-permuted k-axis, in-register) ----
      short8 pf[4];
      #pragma unroll
      for (int ks = 0; ks < 4; ++ks)
        #pragma unroll
        for (int j = 0; j < 8; ++j)
          pf[ks][j] = (short)f2bf(sc[ks >> 1][8 * (ks & 1) + j]);

      // ---- PV ----
      __builtin_amdgcn_s_setprio(1);
      #pragma unroll
      for (int dg = 0; dg < 2; ++dg) {
        const int d = dg * 32 + l31;
        const int hv = (d ^ (d >> 3)) & 7;
        const ushort* vp = &Vt[cur][s2][d * 64];
        #pragma unroll
        for (int ks = 0; ks < 4; ++ks) {
          short8 vf = *(const short8*)&vp[(((ks * 2 + lhalf) ^ hv) & 7) * 8];
          o[dg] = __builtin_amdgcn_mfma_f32_32x32x16_bf16(vf, pf[ks], o[dg], 0, 0, 0);
        }
      }
      __builtin_amdgcn_s_setprio(0);
    }

    // ---- late stage: write prefetched K/V into Ks/Vt[nxt] (vmcnt had full cover) ----
    if (pre) {
      *(short8*)&Ks[nxt][0][tid * 8]        = kr[0];
      *(short8*)&Ks[nxt][0][2048 + tid * 8] = kr[1];
      *(short8*)&Ks[nxt][1][tid * 8]        = kr[2];
      *(short8*)&Ks[nxt][1][2048 + tid * 8] = kr[3];
      #pragma unroll
      for (int s2 = 0; s2 < 2; ++s2)
        #pragma unroll
        for (int dd = 0; dd < 4; ++dd) {
          const int d = d0 + dd;
          const int hd = (d ^ (d >> 3)) & 7;
          us4 w;
          w[0] = vr[s2 * 4 + 0][dd]; w[1] = vr[s2 * 4 + 1][dd];
          w[2] = vr[s2 * 4 + 2][dd]; w[3] = vr[s2 * 4 + 3][dd];
          *(us4*)&Vt[nxt][s2][d * 64 + (((skg >> 1) ^ hd) & 7) * 8 + (skg & 1) * 4] = w;
        }
    }
    __syncthreads();
    cur = nxt;
  }

  // ---- epilogue: O^T/l -> values[bh][q][d] ----
  const float inv = 1.0f / l_run;
  ushort* vout = values + ((size_t)bh * S_ + q) * 64;
  #pragma unroll
  for (int dg = 0; dg < 2; ++dg)
    #pragma unroll
    for (int quad = 0; quad < 4; ++quad) {
      us4 w;
      #pragma unroll
      for (int r = 0; r < 4; ++r) w[r] = f2bf(o[dg][quad * 4 + r] * inv);
      *(us4*)(vout + dg * 32 + quad * 8 + lhalf * 4) = w;
    }
}

// ---------------- launch ----------------

extern "C" void kernel_launch(void* const* d_in, const int* in_sizes, int n_in,
                              void* d_out, int out_size, void* d_ws, size_t ws_size,
                              hipStream_t stream) {
  const float* x    = (const float*)d_in[0];
  const float* mask = (const float*)d_in[1];
  const float* Wqkv = (const float*)d_in[2];
  const float* bqkv = (const float*)d_in[3];
  const float* Wo   = (const float*)d_in[4];
  const float* bo   = (const float*)d_in[5];
  float* out = (float*)d_out;

  char* ws = (char*)d_ws;
  ushort* xbf    = (ushort*)(ws + 0);
  ushort* vals   = (ushort*)(ws + 0);
  ushort* wqkvT  = (ushort*)(ws + 8388608);
  ushort* woT    = (ushort*)(ws + 14680064);
  ushort* qkv    = (ushort*)(ws + 16777216);

  cvt_bf16_vec<<<4096, 256, 0, stream>>>((const float4*)x, xbf, (B_ * S_ * D_) / 4);
  transpose_cvt<<<dim3(3 * D_ / 32, D_ / 32), dim3(32, 8), 0, stream>>>(Wqkv, wqkvT, D_, 3 * D_);
  transpose_cvt<<<dim3(D_ / 32, D_ / 32), dim3(32, 8), 0, stream>>>(Wo, woT, D_, D_);
  gemm_bt<true><<<dim3((B_ * S_) / 128, (3 * D_) / 128), 256, 0, stream>>>(
      xbf, wqkvT, bqkv, qkv, nullptr, B_ * S_, 3 * D_, D_);
  flash_attn<<<dim3(S_ / 128, B_ * H_), 256, 0, stream>>>(qkv, mask, vals);
  gemm_bt<false><<<dim3((B_ * S_) / 128, D_ / 128), 256, 0, stream>>>(
      vals, woT, bo, nullptr, out, B_ * S_, D_, D_);
}

// Round 9
// 184.384 us; speedup vs baseline: 1.4160x; 1.0274x over previous
//
#include <hip/hip_runtime.h>
#include <hip/hip_bf16.h>

#define B_ 2
#define S_ 2048
#define D_ 1024
#define H_ 16
#define HD_ 64

typedef __attribute__((ext_vector_type(8))) short short8;
typedef __attribute__((ext_vector_type(4))) float f32x4;
typedef __attribute__((ext_vector_type(16))) float f32x16;
typedef __attribute__((ext_vector_type(4))) unsigned short us4;

static __device__ __forceinline__ ushort f2bf(float x) {
  __hip_bfloat16 h = __float2bfloat16(x);
  return *reinterpret_cast<ushort*>(&h);
}

static __device__ __forceinline__ void gld_lds16(void* lds, const void* g) {
  __builtin_amdgcn_global_load_lds(
      (__attribute__((address_space(1))) void*)(g),
      (__attribute__((address_space(3))) void*)(lds), 16, 0, 0);
}

// ---------------- conversion kernels ----------------

__global__ __launch_bounds__(256) void cvt_bf16_vec(const float4* __restrict__ in,
                                                    ushort* __restrict__ out, int n4) {
  int i = blockIdx.x * blockDim.x + threadIdx.x;
  if (i < n4) {
    float4 v = in[i];
    ushort4 o;
    o.x = f2bf(v.x); o.y = f2bf(v.y); o.z = f2bf(v.z); o.w = f2bf(v.w);
    *reinterpret_cast<ushort4*>(out + (size_t)i * 4) = o;
  }
}

// in: [K][N] f32 row-major  ->  out: [N][K] bf16 row-major
__global__ __launch_bounds__(256) void transpose_cvt(const float* __restrict__ in,
                                                     ushort* __restrict__ out,
                                                     int K, int N) {
  __shared__ float tile[32][33];
  const int bn = blockIdx.x * 32, bk = blockIdx.y * 32;
  const int tx = threadIdx.x, ty = threadIdx.y;
  #pragma unroll
  for (int i = ty; i < 32; i += 8)
    tile[i][tx] = in[(size_t)(bk + i) * N + bn + tx];
  __syncthreads();
  #pragma unroll
  for (int i = ty; i < 32; i += 8)
    out[(size_t)(bn + i) * K + bk + tx] = f2bf(tile[tx][i]);
}

// ---------------- GEMM: C = A @ Bt^T + bias ----------------
template <bool OUT_BF16>
__global__ __launch_bounds__(256) void gemm_bt(const ushort* __restrict__ A,
                                               const ushort* __restrict__ Bt,
                                               const float* __restrict__ bias,
                                               ushort* __restrict__ Cb,
                                               float* __restrict__ Cf,
                                               int M, int N, int K) {
  __shared__ __align__(16) ushort As[128 * 32];
  __shared__ __align__(16) ushort Bs[128 * 32];
  const int tid = threadIdx.x;
  const int lane = tid & 63, wid = tid >> 6;
  const int wr = wid >> 1, wc = wid & 1;
  const int row0 = blockIdx.x * 128, col0 = blockIdx.y * 128;
  const int l15 = lane & 15, lhi = lane >> 4;

  f32x4 acc[4][4];
  #pragma unroll
  for (int i = 0; i < 4; ++i)
    #pragma unroll
    for (int j = 0; j < 4; ++j)
      acc[i][j] = f32x4{0.f, 0.f, 0.f, 0.f};

  const int sr = tid >> 2;
  const int scol = (tid & 3) * 8;

  for (int k0 = 0; k0 < K; k0 += 32) {
    gld_lds16(&As[(size_t)tid * 8],        &A[(size_t)(row0 + sr) * K + k0 + scol]);
    gld_lds16(&As[2048 + (size_t)tid * 8], &A[(size_t)(row0 + 64 + sr) * K + k0 + scol]);
    gld_lds16(&Bs[(size_t)tid * 8],        &Bt[(size_t)(col0 + sr) * K + k0 + scol]);
    gld_lds16(&Bs[2048 + (size_t)tid * 8], &Bt[(size_t)(col0 + 64 + sr) * K + k0 + scol]);
    __syncthreads();

    short8 af[4], bfr[4];
    #pragma unroll
    for (int mt = 0; mt < 4; ++mt)
      af[mt] = *(const short8*)&As[(wr * 64 + mt * 16 + l15) * 32 + lhi * 8];
    #pragma unroll
    for (int nt = 0; nt < 4; ++nt)
      bfr[nt] = *(const short8*)&Bs[(wc * 64 + nt * 16 + l15) * 32 + lhi * 8];
    #pragma unroll
    for (int mt = 0; mt < 4; ++mt)
      #pragma unroll
      for (int nt = 0; nt < 4; ++nt)
        acc[mt][nt] = __builtin_amdgcn_mfma_f32_16x16x32_bf16(af[mt], bfr[nt], acc[mt][nt], 0, 0, 0);
    __syncthreads();
  }

  const int orow = row0 + wr * 64;
  const int ocol = col0 + wc * 64 + l15;
  #pragma unroll
  for (int mt = 0; mt < 4; ++mt) {
    #pragma unroll
    for (int nt = 0; nt < 4; ++nt) {
      const int gc = ocol + nt * 16;
      const float bv = bias[gc];
      #pragma unroll
      for (int r = 0; r < 4; ++r) {
        const int gr = orow + mt * 16 + lhi * 4 + r;
        const float v = acc[mt][nt][r] + bv;
        if (OUT_BF16) Cb[(size_t)gr * N + gc] = f2bf(v);
        else          Cf[(size_t)gr * N + gc] = v;
      }
    }
  }
}

// ---------------- flash attention, 32x32 MFMA, T15 2-deep pipeline ----------------
// Round-4 verified layouts/math.  New: QK(t+1) is computed at iteration t (scA/scB
// register ping-pong, 2x-unrolled loop, static indexing) so softmax(t) -- a pure
// VALU chain -- has no dependency on the in-flight QK MFMAs and overlaps them.
// Single mask buffer per iteration (mask is L2-resident: 16 head-blocks on the
// same XCD share each tile).  Defer-max (T13, THR=8).
__global__ __launch_bounds__(256, 2) void flash_attn(const ushort* __restrict__ qkv,
                                                     const float* __restrict__ mask,
                                                     ushort* __restrict__ values) {
  __shared__ __align__(16) ushort Ks[2][64 * 64];
  __shared__ __align__(16) ushort Vt[2][64 * 64];

  const int tid = threadIdx.x;
  const int lane = tid & 63, wid = tid >> 6;
  const int l31 = lane & 31, lhalf = lane >> 5;
  const int qt = blockIdx.x, bh = blockIdx.y, b = bh >> 4, h = bh & 15;
  const size_t base = (size_t)b * S_ * 3072 + (size_t)h * 192;
  const int q = qt * 128 + wid * 32 + l31;
  const int NT = S_ / 64;

  // Q B-frags: qf[kd] = Q[q][kd*16 + lhalf*8 + 0..7]
  short8 qf[4];
  {
    const ushort* qrow = qkv + base + (size_t)q * 3072 + lhalf * 8;
    qf[0] = *(const short8*)(qrow);
    qf[1] = *(const short8*)(qrow + 16);
    qf[2] = *(const short8*)(qrow + 32);
    qf[3] = *(const short8*)(qrow + 48);
  }

  const int srow = tid >> 3, sch = tid & 7;
  const int hsr = (srow ^ (srow >> 3)) & 7;
  const int scs = sch ^ hsr;
  const int kg = tid & 15, d0 = (tid >> 4) * 4;
  const int skg = (kg & 12) | ((kg & 1) << 1) | ((kg >> 1) & 1);

  float m_run = -3.0e38f, l_run = 0.f;
  f32x16 o[2];
  #pragma unroll
  for (int dg = 0; dg < 2; ++dg)
    #pragma unroll
    for (int i = 0; i < 16; ++i) o[dg][i] = 0.f;

  const float* mrow = mask + ((size_t)b * S_ + q) * S_;
  us4 vr[4];
  f32x16 scA[2], scB[2];

#define QKT_(SCDST, KSBUF)                                                     \
  {                                                                            \
    _Pragma("unroll")                                                          \
    for (int g = 0; g < 2; ++g) {                                              \
      const int row_ = g * 32 + l31;                                           \
      const int hk_ = (row_ ^ (row_ >> 3)) & 7;                                \
      const ushort* kp_ = &(KSBUF)[row_ * 64];                                 \
      f32x16 s_;                                                               \
      _Pragma("unroll")                                                        \
      for (int i = 0; i < 16; ++i) s_[i] = 0.f;                                \
      _Pragma("unroll")                                                        \
      for (int kd = 0; kd < 4; ++kd) {                                         \
        short8 kf_ = *(const short8*)&kp_[(((kd * 2 + lhalf) ^ hk_) & 7) * 8]; \
        s_ = __builtin_amdgcn_mfma_f32_32x32x16_bf16(kf_, qf[kd], s_, 0, 0, 0);\
      }                                                                        \
      (SCDST)[g] = s_;                                                         \
    }                                                                          \
  }

#define VSCATTER_(VTBUF)                                                       \
  {                                                                            \
    _Pragma("unroll")                                                          \
    for (int dd = 0; dd < 4; ++dd) {                                           \
      const int d_ = d0 + dd;                                                  \
      const int hd_ = (d_ ^ (d_ >> 3)) & 7;                                    \
      us4 w_;                                                                  \
      w_[0] = vr[0][dd]; w_[1] = vr[1][dd];                                    \
      w_[2] = vr[2][dd]; w_[3] = vr[3][dd];                                    \
      *(us4*)&(VTBUF)[d_ * 64 + (((skg >> 1) ^ hd_) & 7) * 8 + (skg & 1) * 4] = w_; \
    }                                                                          \
  }

#define HALF_(T, SCCUR, SCNEXT)                                                \
  {                                                                            \
    const int t_ = (T);                                                        \
    const bool pre1_ = (t_ + 1 < NT), pre2_ = (t_ + 2 < NT);                   \
    if (pre2_) {                                                               \
      const ushort* kn_ = qkv + base + (size_t)(t_ + 2) * 64 * 3072 +          \
                          (size_t)srow * 3072 + 64;                            \
      gld_lds16(&Ks[t_ & 1][tid * 8],        kn_ + scs * 8);                   \
      gld_lds16(&Ks[t_ & 1][2048 + tid * 8], kn_ + (size_t)32 * 3072 + (scs ^ 4) * 8); \
    }                                                                          \
    if (pre1_) {                                                               \
      const ushort* vn_ = qkv + base + (size_t)(t_ + 1) * 64 * 3072 + 128 + d0;\
      _Pragma("unroll")                                                        \
      for (int kk = 0; kk < 4; ++kk)                                           \
        vr[kk] = *(const us4*)(vn_ + (size_t)(kg * 4 + kk) * 3072);            \
    }                                                                          \
    f32x4 mk_[8];                                                              \
    {                                                                          \
      const float* mp_ = mrow + t_ * 64 + lhalf * 4;                           \
      _Pragma("unroll")                                                        \
      for (int i = 0; i < 8; ++i)                                              \
        mk_[i] = *(const f32x4*)(mp_ + (i >> 2) * 32 + (i & 3) * 8);           \
    }                                                                          \
    __builtin_amdgcn_s_setprio(1);                                             \
    if (pre1_) QKT_(SCNEXT, Ks[(t_ + 1) & 1]);                                 \
    /* softmax on SCCUR (independent of the QK MFMAs above) */                 \
    _Pragma("unroll")                                                          \
    for (int g = 0; g < 2; ++g)                                                \
      _Pragma("unroll")                                                        \
      for (int r = 0; r < 16; ++r)                                             \
        (SCCUR)[g][r] = (SCCUR)[g][r] * 0.125f + mk_[g * 4 + (r >> 2)][r & 3]; \
    float mx_ = (SCCUR)[0][0];                                                 \
    _Pragma("unroll")                                                          \
    for (int g = 0; g < 2; ++g)                                                \
      _Pragma("unroll")                                                        \
      for (int r = 0; r < 16; ++r) mx_ = fmaxf(mx_, (SCCUR)[g][r]);            \
    mx_ = fmaxf(mx_, __shfl_xor(mx_, 32));                                     \
    if (__any(mx_ > m_run + 8.0f)) {                                           \
      const float mnew_ = fmaxf(m_run, mx_);                                   \
      const float alpha_ = __expf(m_run - mnew_);                              \
      m_run = mnew_;                                                           \
      l_run *= alpha_;                                                         \
      _Pragma("unroll")                                                        \
      for (int dg = 0; dg < 2; ++dg)                                           \
        _Pragma("unroll")                                                      \
        for (int i = 0; i < 16; ++i) o[dg][i] *= alpha_;                       \
    }                                                                          \
    float ps_ = 0.f;                                                           \
    _Pragma("unroll")                                                          \
    for (int g = 0; g < 2; ++g)                                                \
      _Pragma("unroll")                                                        \
      for (int r = 0; r < 16; ++r) {                                           \
        const float p_ = __expf((SCCUR)[g][r] - m_run);                        \
        (SCCUR)[g][r] = p_;                                                    \
        ps_ += p_;                                                             \
      }                                                                        \
    ps_ += __shfl_xor(ps_, 32);                                                \
    l_run += ps_;                                                              \
    short8 pf_[4];                                                             \
    _Pragma("unroll")                                                          \
    for (int ks = 0; ks < 4; ++ks)                                             \
      _Pragma("unroll")                                                        \
      for (int j = 0; j < 8; ++j)                                              \
        pf_[ks][j] = (short)f2bf((SCCUR)[ks >> 1][8 * (ks & 1) + j]);          \
    _Pragma("unroll")                                                          \
    for (int dg = 0; dg < 2; ++dg) {                                           \
      const int d_ = dg * 32 + l31;                                            \
      const int hv_ = (d_ ^ (d_ >> 3)) & 7;                                    \
      const ushort* vp_ = &Vt[t_ & 1][d_ * 64];                                \
      _Pragma("unroll")                                                        \
      for (int ks = 0; ks < 4; ++ks) {                                         \
        short8 vf_ = *(const short8*)&vp_[(((ks * 2 + lhalf) ^ hv_) & 7) * 8]; \
        o[dg] = __builtin_amdgcn_mfma_f32_32x32x16_bf16(vf_, pf_[ks], o[dg], 0, 0, 0); \
      }                                                                        \
    }                                                                          \
    __builtin_amdgcn_s_setprio(0);                                             \
    if (pre1_) VSCATTER_(Vt[(t_ + 1) & 1]);                                    \
    __syncthreads();                                                           \
  }

  // ---- prologue: stage K(0),K(1) -> LDS, V(0) -> Vt[0]; then QK(0) -> scA ----
  {
    const ushort* k0 = qkv + base + (size_t)srow * 3072 + 64;
    gld_lds16(&Ks[0][tid * 8],        k0 + scs * 8);
    gld_lds16(&Ks[0][2048 + tid * 8], k0 + (size_t)32 * 3072 + (scs ^ 4) * 8);
    const ushort* k1 = k0 + (size_t)64 * 3072;
    gld_lds16(&Ks[1][tid * 8],        k1 + scs * 8);
    gld_lds16(&Ks[1][2048 + tid * 8], k1 + (size_t)32 * 3072 + (scs ^ 4) * 8);
    #pragma unroll
    for (int kk = 0; kk < 4; ++kk)
      vr[kk] = *(const us4*)(qkv + base + (size_t)(kg * 4 + kk) * 3072 + 128 + d0);
    VSCATTER_(Vt[0]);
    __syncthreads();
    QKT_(scA, Ks[0]);
  }

  for (int tp = 0; tp < NT; tp += 2) {
    HALF_(tp,     scA, scB);
    HALF_(tp + 1, scB, scA);
  }

  // ---- epilogue: O^T/l -> values[bh][q][d] ----
  const float inv = 1.0f / l_run;
  ushort* vout = values + ((size_t)bh * S_ + q) * 64;
  #pragma unroll
  for (int dg = 0; dg < 2; ++dg)
    #pragma unroll
    for (int quad = 0; quad < 4; ++quad) {
      us4 w;
      #pragma unroll
      for (int r = 0; r < 4; ++r) w[r] = f2bf(o[dg][quad * 4 + r] * inv);
      *(us4*)(vout + dg * 32 + quad * 8 + lhalf * 4) = w;
    }
#undef HALF_
#undef VSCATTER_
#undef QKT_
}

// ---------------- launch ----------------

extern "C" void kernel_launch(void* const* d_in, const int* in_sizes, int n_in,
                              void* d_out, int out_size, void* d_ws, size_t ws_size,
                              hipStream_t stream) {
  const float* x    = (const float*)d_in[0];
  const float* mask = (const float*)d_in[1];
  const float* Wqkv = (const float*)d_in[2];
  const float* bqkv = (const float*)d_in[3];
  const float* Wo   = (const float*)d_in[4];
  const float* bo   = (const float*)d_in[5];
  float* out = (float*)d_out;

  char* ws = (char*)d_ws;
  ushort* xbf    = (ushort*)(ws + 0);
  ushort* vals   = (ushort*)(ws + 0);
  ushort* wqkvT  = (ushort*)(ws + 8388608);
  ushort* woT    = (ushort*)(ws + 14680064);
  ushort* qkv    = (ushort*)(ws + 16777216);

  cvt_bf16_vec<<<4096, 256, 0, stream>>>((const float4*)x, xbf, (B_ * S_ * D_) / 4);
  transpose_cvt<<<dim3(3 * D_ / 32, D_ / 32), dim3(32, 8), 0, stream>>>(Wqkv, wqkvT, D_, 3 * D_);
  transpose_cvt<<<dim3(D_ / 32, D_ / 32), dim3(32, 8), 0, stream>>>(Wo, woT, D_, D_);
  gemm_bt<true><<<dim3((B_ * S_) / 128, (3 * D_) / 128), 256, 0, stream>>>(
      xbf, wqkvT, bqkv, qkv, nullptr, B_ * S_, 3 * D_, D_);
  flash_attn<<<dim3(S_ / 128, B_ * H_), 256, 0, stream>>>(qkv, mask, vals);
  gemm_bt<false><<<dim3((B_ * S_) / 128, D_ / 128), 256, 0, stream>>>(
      vals, woT, bo, nullptr, out, B_ * S_, D_, D_);
}

// Round 10
// 182.016 us; speedup vs baseline: 1.4344x; 1.0130x over previous
//
#include <hip/hip_runtime.h>
#include <hip/hip_bf16.h>

#define B_ 2
#define S_ 2048
#define D_ 1024
#define H_ 16
#define HD_ 64

typedef __attribute__((ext_vector_type(8))) short short8;
typedef __attribute__((ext_vector_type(4))) float f32x4;
typedef __attribute__((ext_vector_type(16))) float f32x16;
typedef __attribute__((ext_vector_type(4))) unsigned short us4;

static __device__ __forceinline__ ushort f2bf(float x) {
  __hip_bfloat16 h = __float2bfloat16(x);
  return *reinterpret_cast<ushort*>(&h);
}

static __device__ __forceinline__ void gld_lds16(void* lds, const void* g) {
  __builtin_amdgcn_global_load_lds(
      (__attribute__((address_space(1))) void*)(g),
      (__attribute__((address_space(3))) void*)(lds), 16, 0, 0);
}

// ---------------- fused prep: x->bf16 + Wqkv^T + Wo^T in ONE launch ----------------

static __device__ __forceinline__ void transpose_tile(const float* __restrict__ in,
                                                      ushort* __restrict__ out,
                                                      int K, int N, int bn, int bk,
                                                      int tx, int ty) {
  __shared__ float tile[32][33];
  #pragma unroll
  for (int i = ty; i < 32; i += 8)
    tile[i][tx] = in[(size_t)(bk + i) * N + bn + tx];
  __syncthreads();
  #pragma unroll
  for (int i = ty; i < 32; i += 8)
    out[(size_t)(bn + i) * K + bk + tx] = f2bf(tile[tx][i]);
}

// grid: [0,4096) cvt x | [4096,7168) Wqkv^T (96x32 tiles) | [7168,8192) Wo^T (32x32)
__global__ __launch_bounds__(256) void prep_all(const float4* __restrict__ x4,
                                                ushort* __restrict__ xbf,
                                                const float* __restrict__ Wqkv,
                                                ushort* __restrict__ wqkvT,
                                                const float* __restrict__ Wo,
                                                ushort* __restrict__ woT) {
  const int blk = blockIdx.x, tid = threadIdx.x;
  if (blk < 4096) {
    const int i = blk * 256 + tid;
    float4 v = x4[i];
    ushort4 o;
    o.x = f2bf(v.x); o.y = f2bf(v.y); o.z = f2bf(v.z); o.w = f2bf(v.w);
    *reinterpret_cast<ushort4*>(xbf + (size_t)i * 4) = o;
  } else if (blk < 7168) {
    const int sub = blk - 4096;
    transpose_tile(Wqkv, wqkvT, D_, 3 * D_, (sub % 96) * 32, (sub / 96) * 32,
                   tid & 31, tid >> 5);
  } else {
    const int sub = blk - 7168;
    transpose_tile(Wo, woT, D_, D_, (sub % 32) * 32, (sub / 32) * 32,
                   tid & 31, tid >> 5);
  }
}

// ---------------- GEMM: C = A @ Bt^T + bias (T1 XCD-chunked tile swizzle) ----------------
template <bool OUT_BF16>
__global__ __launch_bounds__(256) void gemm_bt(const ushort* __restrict__ A,
                                               const ushort* __restrict__ Bt,
                                               const float* __restrict__ bias,
                                               ushort* __restrict__ Cb,
                                               float* __restrict__ Cf,
                                               int M, int N, int K) {
  __shared__ __align__(16) ushort As[128 * 32];
  __shared__ __align__(16) ushort Bs[128 * 32];
  const int tid = threadIdx.x;
  const int lane = tid & 63, wid = tid >> 6;
  const int wr = wid >> 1, wc = wid & 1;

  // XCD-chunked relabel: hw-linear id -> contiguous tile chunk per XCD.
  // Requires nwg % 8 == 0 (768 and 256 here) -> bijective.
  const int nwg = gridDim.x * gridDim.y;
  const int lin = blockIdx.x + gridDim.x * blockIdx.y;
  const int nl = (lin & 7) * (nwg >> 3) + (lin >> 3);
  const int row0 = (nl % gridDim.x) * 128, col0 = (nl / gridDim.x) * 128;

  const int l15 = lane & 15, lhi = lane >> 4;

  f32x4 acc[4][4];
  #pragma unroll
  for (int i = 0; i < 4; ++i)
    #pragma unroll
    for (int j = 0; j < 4; ++j)
      acc[i][j] = f32x4{0.f, 0.f, 0.f, 0.f};

  const int sr = tid >> 2;
  const int scol = (tid & 3) * 8;

  for (int k0 = 0; k0 < K; k0 += 32) {
    gld_lds16(&As[(size_t)tid * 8],        &A[(size_t)(row0 + sr) * K + k0 + scol]);
    gld_lds16(&As[2048 + (size_t)tid * 8], &A[(size_t)(row0 + 64 + sr) * K + k0 + scol]);
    gld_lds16(&Bs[(size_t)tid * 8],        &Bt[(size_t)(col0 + sr) * K + k0 + scol]);
    gld_lds16(&Bs[2048 + (size_t)tid * 8], &Bt[(size_t)(col0 + 64 + sr) * K + k0 + scol]);
    __syncthreads();

    short8 af[4], bfr[4];
    #pragma unroll
    for (int mt = 0; mt < 4; ++mt)
      af[mt] = *(const short8*)&As[(wr * 64 + mt * 16 + l15) * 32 + lhi * 8];
    #pragma unroll
    for (int nt = 0; nt < 4; ++nt)
      bfr[nt] = *(const short8*)&Bs[(wc * 64 + nt * 16 + l15) * 32 + lhi * 8];
    #pragma unroll
    for (int mt = 0; mt < 4; ++mt)
      #pragma unroll
      for (int nt = 0; nt < 4; ++nt)
        acc[mt][nt] = __builtin_amdgcn_mfma_f32_16x16x32_bf16(af[mt], bfr[nt], acc[mt][nt], 0, 0, 0);
    __syncthreads();
  }

  const int orow = row0 + wr * 64;
  const int ocol = col0 + wc * 64 + l15;
  #pragma unroll
  for (int mt = 0; mt < 4; ++mt) {
    #pragma unroll
    for (int nt = 0; nt < 4; ++nt) {
      const int gc = ocol + nt * 16;
      const float bv = bias[gc];
      #pragma unroll
      for (int r = 0; r < 4; ++r) {
        const int gr = orow + mt * 16 + lhi * 4 + r;
        const float v = acc[mt][nt][r] + bv;
        if (OUT_BF16) Cb[(size_t)gr * N + gc] = f2bf(v);
        else          Cf[(size_t)gr * N + gc] = v;
      }
    }
  }
}

// ---------------- flash attention, 32x32 MFMA, T15 2-deep pipeline (FROZEN r9) ----------------
__global__ __launch_bounds__(256, 2) void flash_attn(const ushort* __restrict__ qkv,
                                                     const float* __restrict__ mask,
                                                     ushort* __restrict__ values) {
  __shared__ __align__(16) ushort Ks[2][64 * 64];
  __shared__ __align__(16) ushort Vt[2][64 * 64];

  const int tid = threadIdx.x;
  const int lane = tid & 63, wid = tid >> 6;
  const int l31 = lane & 31, lhalf = lane >> 5;
  const int qt = blockIdx.x, bh = blockIdx.y, b = bh >> 4, h = bh & 15;
  const size_t base = (size_t)b * S_ * 3072 + (size_t)h * 192;
  const int q = qt * 128 + wid * 32 + l31;
  const int NT = S_ / 64;

  short8 qf[4];
  {
    const ushort* qrow = qkv + base + (size_t)q * 3072 + lhalf * 8;
    qf[0] = *(const short8*)(qrow);
    qf[1] = *(const short8*)(qrow + 16);
    qf[2] = *(const short8*)(qrow + 32);
    qf[3] = *(const short8*)(qrow + 48);
  }

  const int srow = tid >> 3, sch = tid & 7;
  const int hsr = (srow ^ (srow >> 3)) & 7;
  const int scs = sch ^ hsr;
  const int kg = tid & 15, d0 = (tid >> 4) * 4;
  const int skg = (kg & 12) | ((kg & 1) << 1) | ((kg >> 1) & 1);

  float m_run = -3.0e38f, l_run = 0.f;
  f32x16 o[2];
  #pragma unroll
  for (int dg = 0; dg < 2; ++dg)
    #pragma unroll
    for (int i = 0; i < 16; ++i) o[dg][i] = 0.f;

  const float* mrow = mask + ((size_t)b * S_ + q) * S_;
  us4 vr[4];
  f32x16 scA[2], scB[2];

#define QKT_(SCDST, KSBUF)                                                     \
  {                                                                            \
    _Pragma("unroll")                                                          \
    for (int g = 0; g < 2; ++g) {                                              \
      const int row_ = g * 32 + l31;                                           \
      const int hk_ = (row_ ^ (row_ >> 3)) & 7;                                \
      const ushort* kp_ = &(KSBUF)[row_ * 64];                                 \
      f32x16 s_;                                                               \
      _Pragma("unroll")                                                        \
      for (int i = 0; i < 16; ++i) s_[i] = 0.f;                                \
      _Pragma("unroll")                                                        \
      for (int kd = 0; kd < 4; ++kd) {                                         \
        short8 kf_ = *(const short8*)&kp_[(((kd * 2 + lhalf) ^ hk_) & 7) * 8]; \
        s_ = __builtin_amdgcn_mfma_f32_32x32x16_bf16(kf_, qf[kd], s_, 0, 0, 0);\
      }                                                                        \
      (SCDST)[g] = s_;                                                         \
    }                                                                          \
  }

#define VSCATTER_(VTBUF)                                                       \
  {                                                                            \
    _Pragma("unroll")                                                          \
    for (int dd = 0; dd < 4; ++dd) {                                           \
      const int d_ = d0 + dd;                                                  \
      const int hd_ = (d_ ^ (d_ >> 3)) & 7;                                    \
      us4 w_;                                                                  \
      w_[0] = vr[0][dd]; w_[1] = vr[1][dd];                                    \
      w_[2] = vr[2][dd]; w_[3] = vr[3][dd];                                    \
      *(us4*)&(VTBUF)[d_ * 64 + (((skg >> 1) ^ hd_) & 7) * 8 + (skg & 1) * 4] = w_; \
    }                                                                          \
  }

#define HALF_(T, SCCUR, SCNEXT)                                                \
  {                                                                            \
    const int t_ = (T);                                                        \
    const bool pre1_ = (t_ + 1 < NT), pre2_ = (t_ + 2 < NT);                   \
    if (pre2_) {                                                               \
      const ushort* kn_ = qkv + base + (size_t)(t_ + 2) * 64 * 3072 +          \
                          (size_t)srow * 3072 + 64;                            \
      gld_lds16(&Ks[t_ & 1][tid * 8],        kn_ + scs * 8);                   \
      gld_lds16(&Ks[t_ & 1][2048 + tid * 8], kn_ + (size_t)32 * 3072 + (scs ^ 4) * 8); \
    }                                                                          \
    if (pre1_) {                                                               \
      const ushort* vn_ = qkv + base + (size_t)(t_ + 1) * 64 * 3072 + 128 + d0;\
      _Pragma("unroll")                                                        \
      for (int kk = 0; kk < 4; ++kk)                                           \
        vr[kk] = *(const us4*)(vn_ + (size_t)(kg * 4 + kk) * 3072);            \
    }                                                                          \
    f32x4 mk_[8];                                                              \
    {                                                                          \
      const float* mp_ = mrow + t_ * 64 + lhalf * 4;                           \
      _Pragma("unroll")                                                        \
      for (int i = 0; i < 8; ++i)                                              \
        mk_[i] = *(const f32x4*)(mp_ + (i >> 2) * 32 + (i & 3) * 8);           \
    }                                                                          \
    __builtin_amdgcn_s_setprio(1);                                             \
    if (pre1_) QKT_(SCNEXT, Ks[(t_ + 1) & 1]);                                 \
    _Pragma("unroll")                                                          \
    for (int g = 0; g < 2; ++g)                                                \
      _Pragma("unroll")                                                        \
      for (int r = 0; r < 16; ++r)                                             \
        (SCCUR)[g][r] = (SCCUR)[g][r] * 0.125f + mk_[g * 4 + (r >> 2)][r & 3]; \
    float mx_ = (SCCUR)[0][0];                                                 \
    _Pragma("unroll")                                                          \
    for (int g = 0; g < 2; ++g)                                                \
      _Pragma("unroll")                                                        \
      for (int r = 0; r < 16; ++r) mx_ = fmaxf(mx_, (SCCUR)[g][r]);            \
    mx_ = fmaxf(mx_, __shfl_xor(mx_, 32));                                     \
    if (__any(mx_ > m_run + 8.0f)) {                                           \
      const float mnew_ = fmaxf(m_run, mx_);                                   \
      const float alpha_ = __expf(m_run - mnew_);                              \
      m_run = mnew_;                                                           \
      l_run *= alpha_;                                                         \
      _Pragma("unroll")                                                        \
      for (int dg = 0; dg < 2; ++dg)                                           \
        _Pragma("unroll")                                                      \
        for (int i = 0; i < 16; ++i) o[dg][i] *= alpha_;                       \
    }                                                                          \
    float ps_ = 0.f;                                                           \
    _Pragma("unroll")                                                          \
    for (int g = 0; g < 2; ++g)                                                \
      _Pragma("unroll")                                                        \
      for (int r = 0; r < 16; ++r) {                                           \
        const float p_ = __expf((SCCUR)[g][r] - m_run);                        \
        (SCCUR)[g][r] = p_;                                                    \
        ps_ += p_;                                                             \
      }                                                                        \
    ps_ += __shfl_xor(ps_, 32);                                                \
    l_run += ps_;                                                              \
    short8 pf_[4];                                                             \
    _Pragma("unroll")                                                          \
    for (int ks = 0; ks < 4; ++ks)                                             \
      _Pragma("unroll")                                                        \
      for (int j = 0; j < 8; ++j)                                              \
        pf_[ks][j] = (short)f2bf((SCCUR)[ks >> 1][8 * (ks & 1) + j]);          \
    _Pragma("unroll")                                                          \
    for (int dg = 0; dg < 2; ++dg) {                                           \
      const int d_ = dg * 32 + l31;                                            \
      const int hv_ = (d_ ^ (d_ >> 3)) & 7;                                    \
      const ushort* vp_ = &Vt[t_ & 1][d_ * 64];                                \
      _Pragma("unroll")                                                        \
      for (int ks = 0; ks < 4; ++ks) {                                         \
        short8 vf_ = *(const short8*)&vp_[(((ks * 2 + lhalf) ^ hv_) & 7) * 8]; \
        o[dg] = __builtin_amdgcn_mfma_f32_32x32x16_bf16(vf_, pf_[ks], o[dg], 0, 0, 0); \
      }                                                                        \
    }                                                                          \
    __builtin_amdgcn_s_setprio(0);                                             \
    if (pre1_) VSCATTER_(Vt[(t_ + 1) & 1]);                                    \
    __syncthreads();                                                           \
  }

  {
    const ushort* k0 = qkv + base + (size_t)srow * 3072 + 64;
    gld_lds16(&Ks[0][tid * 8],        k0 + scs * 8);
    gld_lds16(&Ks[0][2048 + tid * 8], k0 + (size_t)32 * 3072 + (scs ^ 4) * 8);
    const ushort* k1 = k0 + (size_t)64 * 3072;
    gld_lds16(&Ks[1][tid * 8],        k1 + scs * 8);
    gld_lds16(&Ks[1][2048 + tid * 8], k1 + (size_t)32 * 3072 + (scs ^ 4) * 8);
    #pragma unroll
    for (int kk = 0; kk < 4; ++kk)
      vr[kk] = *(const us4*)(qkv + base + (size_t)(kg * 4 + kk) * 3072 + 128 + d0);
    VSCATTER_(Vt[0]);
    __syncthreads();
    QKT_(scA, Ks[0]);
  }

  for (int tp = 0; tp < NT; tp += 2) {
    HALF_(tp,     scA, scB);
    HALF_(tp + 1, scB, scA);
  }

  const float inv = 1.0f / l_run;
  ushort* vout = values + ((size_t)bh * S_ + q) * 64;
  #pragma unroll
  for (int dg = 0; dg < 2; ++dg)
    #pragma unroll
    for (int quad = 0; quad < 4; ++quad) {
      us4 w;
      #pragma unroll
      for (int r = 0; r < 4; ++r) w[r] = f2bf(o[dg][quad * 4 + r] * inv);
      *(us4*)(vout + dg * 32 + quad * 8 + lhalf * 4) = w;
    }
#undef HALF_
#undef VSCATTER_
#undef QKT_
}

// ---------------- launch ----------------

extern "C" void kernel_launch(void* const* d_in, const int* in_sizes, int n_in,
                              void* d_out, int out_size, void* d_ws, size_t ws_size,
                              hipStream_t stream) {
  const float* x    = (const float*)d_in[0];
  const float* mask = (const float*)d_in[1];
  const float* Wqkv = (const float*)d_in[2];
  const float* bqkv = (const float*)d_in[3];
  const float* Wo   = (const float*)d_in[4];
  const float* bo   = (const float*)d_in[5];
  float* out = (float*)d_out;

  char* ws = (char*)d_ws;
  ushort* xbf    = (ushort*)(ws + 0);
  ushort* vals   = (ushort*)(ws + 0);
  ushort* wqkvT  = (ushort*)(ws + 8388608);
  ushort* woT    = (ushort*)(ws + 14680064);
  ushort* qkv    = (ushort*)(ws + 16777216);

  prep_all<<<8192, 256, 0, stream>>>((const float4*)x, xbf, Wqkv, wqkvT, Wo, woT);
  gemm_bt<true><<<dim3((B_ * S_) / 128, (3 * D_) / 128), 256, 0, stream>>>(
      xbf, wqkvT, bqkv, qkv, nullptr, B_ * S_, 3 * D_, D_);
  flash_attn<<<dim3(S_ / 128, B_ * H_), 256, 0, stream>>>(qkv, mask, vals);
  gemm_bt<false><<<dim3((B_ * S_) / 128, D_ / 128), 256, 0, stream>>>(
      vals, woT, bo, nullptr, out, B_ * S_, D_, D_);
}